// Round 5
// baseline (619.014 us; speedup 1.0000x reference)
//
#include <hip/hip_runtime.h>
#include <hip/hip_bf16.h>

typedef _Float16 f16;
typedef f16 f16x4 __attribute__((ext_vector_type(4)));
typedef f16 f16x8 __attribute__((ext_vector_type(8)));
typedef __fp16 h16x2 __attribute__((ext_vector_type(2)));
typedef __fp16 h16x4 __attribute__((ext_vector_type(4)));
typedef float f32x4 __attribute__((ext_vector_type(4)));
typedef float f32x16 __attribute__((ext_vector_type(16)));

#define MT 128          // points per block (2 blocks/CU -> 4 waves/SIMD)
#define LDST 260        // f16 LDS row stride: 520 B -> 2-way (free) bank pattern, 8B aligned
#define INV2PI 0.15915494309189535f

// ---------------- prep: fragment-major Wt ----------------
// wt layout: frag[(layer*8 + wcblk)*16 + kblk][lane][8]  (1 KB per frag, lane-major)
// A[i=lane&31][k = kblk*16 + (lane>>5)*8 + j] = wh[layer][k][wcblk*32 + (lane&31)]
__global__ __launch_bounds__(64)
void prep_wt(const float* __restrict__ wh, f16* __restrict__ wt) {
    const int b = blockIdx.x;                 // 512 = layer(4) x wcblk(8) x kblk(16)
    const int layer = b >> 7, wcblk = (b >> 4) & 7, kblk = b & 15;
    const int lane = threadIdx.x;
    const int l31 = lane & 31, lh = lane >> 5;
    const float* src = wh + layer * 65536 + (kblk * 16 + lh * 8) * 256 + wcblk * 32 + l31;
    f16x8 v;
#pragma unroll
    for (int j = 0; j < 8; j++) v[j] = (f16)src[j * 256];   // 128B-coalesced per half-wave
    *(f16x8*)(wt + b * 512 + lane * 8) = v;                  // 1KB coalesced store
}

// ---------------- fused SIREN ----------------
__device__ inline f16x8 lds_ld8(const f16* p) {
    // two 8B LDS loads (rows are 8B- but not 16B-aligned with LDST=260)
    f16x4 lo = *(const f16x4*)p;
    f16x4 hi = *(const f16x4*)(p + 4);
    return __builtin_shufflevector(lo, hi, 0, 1, 2, 3, 4, 5, 6, 7);
}

__device__ inline f16x4 pk4(float z0, float z1, float z2, float z3) {
    h16x2 a = __builtin_amdgcn_cvt_pkrtz(z0, z1);
    h16x2 b = __builtin_amdgcn_cvt_pkrtz(z2, z3);
    h16x4 r = __builtin_shufflevector(a, b, 0, 1, 2, 3);
    return __builtin_bit_cast(f16x4, r);
}

__global__ __launch_bounds__(512, 4)
void siren_fused(const float* __restrict__ coords,
                 const float* __restrict__ ow1, const float* __restrict__ ob1,
                 const float* __restrict__ ow2, const float* __restrict__ ob2,
                 const float* __restrict__ w0, const float* __restrict__ b0,
                 const f16* __restrict__ wt,    // fragment-major, see prep_wt
                 const float* __restrict__ bh,  // [4][256]
                 const float* __restrict__ wf,  // [256]
                 const float* __restrict__ bf,  // [1]
                 float* __restrict__ out) {
    __shared__ __align__(16) f16 Xs[MT * LDST];   // 66560 B activations
    __shared__ float om_rev[MT];                  // omega / (2*pi)
    __shared__ __align__(16) float crd[MT * 4];
    __shared__ __align__(16) float bh_s[256];
    __shared__ __align__(16) float wf_s[256];

    const int t = threadIdx.x;
    const long base_pt = (long)blockIdx.x * MT;

    // ---- stage coords + wf ----
    if (t < MT) ((f32x4*)crd)[t] = ((const f32x4*)(coords + base_pt * 4))[t];
    if (t < 256) wf_s[t] = wf[t];
    __syncthreads();

    // ---- omega predictor (fp32 vector; threads 0..127, one point each) ----
    if (t < MT) {
        const float c0 = crd[t * 4], c1 = crd[t * 4 + 1], c2 = crd[t * 4 + 2], c3 = crd[t * 4 + 3];
        float h[64];
#pragma unroll
        for (int j = 0; j < 64; j++) {
            float z = ob1[j] + c0 * ow1[j] + c1 * ow1[64 + j] + c2 * ow1[128 + j] + c3 * ow1[192 + j];
            h[j] = fmaxf(z, 0.f);
        }
        float z2 = ob2[0];
#pragma unroll
        for (int j = 0; j < 64; j++) z2 += h[j] * ow2[j];
        const float sig = 1.f / (1.f + __expf(-z2));
        om_rev[t] = (10.f + 90.f * sig) * INV2PI;
    }
    __syncthreads();

    // ---- layer 0 (K=4, fp32 vector): X = sin(omega*(coords@w0+b0)) ----
    {
        const int pt = t >> 2;
        const int ch = (t & 3) * 64;
        const float c0 = crd[pt * 4], c1 = crd[pt * 4 + 1], c2 = crd[pt * 4 + 2], c3 = crd[pt * 4 + 3];
        const float orv = om_rev[pt];
#pragma unroll 4
        for (int c = 0; c < 64; c += 4) {
            f32x4 wv0 = *(const f32x4*)(w0 + 0 * 256 + ch + c);
            f32x4 wv1 = *(const f32x4*)(w0 + 1 * 256 + ch + c);
            f32x4 wv2 = *(const f32x4*)(w0 + 2 * 256 + ch + c);
            f32x4 wv3 = *(const f32x4*)(w0 + 3 * 256 + ch + c);
            f32x4 bv  = *(const f32x4*)(b0 + ch + c);
            float z[4];
#pragma unroll
            for (int j = 0; j < 4; j++) {
                float zz = bv[j] + c0 * wv0[j] + c1 * wv1[j] + c2 * wv2[j] + c3 * wv3[j];
                z[j] = __builtin_amdgcn_sinf(orv * zz);
            }
            *(f16x4*)&Xs[pt * LDST + ch + c] = pk4(z[0], z[1], z[2], z[3]);
        }
    }
    __syncthreads();

    // ---- hidden layers: Z^T = Wt (A) x X (B), 32x32x16 f16 MFMA ----
    // 8 waves: 4 wcol-groups (2 wcblks each) x 2 prow-groups (64 rows).
    // acc = 2x2x16 = 64 AGPR -> fits 128-reg budget for 4 waves/SIMD.
    const int lane = t & 63;
    const int wave = t >> 6;          // 8 waves
    const int l31 = lane & 31;
    const int lh = lane >> 5;         // half-wave: k-offset 8
    const int wcg = wave & 3;         // wcol group: 64 cols
    const int pr0 = (wave >> 2) * 64; // 64 point-rows per wave
    const int wc0 = wcg * 64;

    for (int layer = 0; layer < 4; layer++) {
        if (t < 256) bh_s[t] = bh[layer * 256 + t];   // consumed after mid-barrier

        // A frags for this wave: wcblk0 = wcg*2, frags 512 f16 apart
        const f16* afrag = wt + ((layer * 8 + wcg * 2) * 16) * 512 + lane * 8;
        const f16* bptr = &Xs[(pr0 + l31) * LDST + lh * 8];   // B: lane row = prow

        f32x16 acc[2][2];
#pragma unroll
        for (int ct = 0; ct < 2; ct++)
#pragma unroll
            for (int rt = 0; rt < 2; rt++)
#pragma unroll
                for (int j = 0; j < 16; j++) acc[ct][rt][j] = 0.f;

#pragma unroll
        for (int kb = 0; kb < 16; kb++) {
            f16x8 av0 = *(const f16x8*)(afrag + kb * 512);          // coalesced 1KB
            f16x8 av1 = *(const f16x8*)(afrag + 8192 + kb * 512);   // next wcblk
            f16x8 bv[2];
#pragma unroll
            for (int rt = 0; rt < 2; rt++) bv[rt] = lds_ld8(bptr + rt * 32 * LDST + kb * 16);
#pragma unroll
            for (int rt = 0; rt < 2; rt++) {
                acc[0][rt] = __builtin_amdgcn_mfma_f32_32x32x16_f16(av0, bv[rt], acc[0][rt], 0, 0, 0);
                acc[1][rt] = __builtin_amdgcn_mfma_f32_32x32x16_f16(av1, bv[rt], acc[1][rt], 0, 0, 0);
            }
        }
        __syncthreads();   // all Xs reads done; bh_s staged

        // epilogue: x = sin(om*(z+b)), write f16 back to Xs
        float orv[2];
#pragma unroll
        for (int rt = 0; rt < 2; rt++) orv[rt] = om_rev[pr0 + rt * 32 + l31];
#pragma unroll
        for (int ct = 0; ct < 2; ct++) {
#pragma unroll
            for (int g = 0; g < 4; g++) {
                const int wc = wc0 + ct * 32 + g * 8 + lh * 4;  // D row = (reg&3)+8*(reg>>2)+4*lh
                f32x4 bb = *(const f32x4*)&bh_s[wc];
#pragma unroll
                for (int rt = 0; rt < 2; rt++) {
                    const int prow = pr0 + rt * 32 + l31;       // D col = lane&31
                    float z[4];
#pragma unroll
                    for (int j = 0; j < 4; j++)
                        z[j] = __builtin_amdgcn_sinf(orv[rt] * (acc[ct][rt][g * 4 + j] + bb[j]));
                    *(f16x4*)&Xs[prow * LDST + wc] = pk4(z[0], z[1], z[2], z[3]);  // 8B write
                }
            }
        }
        __syncthreads();
    }

    // ---- final layer: out = X @ wf + bf (fp32 vector) ----
    {
        const int pt = t >> 2;
        const int ch = (t & 3) * 64;
        const f16* xrow = &Xs[pt * LDST + ch];
        float s = 0.f;
#pragma unroll 8
        for (int c = 0; c < 64; c += 4) {
            f16x4 xv = *(const f16x4*)(xrow + c);
            f32x4 wv = *(const f32x4*)&wf_s[ch + c];
            s += (float)xv[0] * wv[0] + (float)xv[1] * wv[1]
               + (float)xv[2] * wv[2] + (float)xv[3] * wv[3];
        }
        s += __shfl_xor(s, 1, 64);
        s += __shfl_xor(s, 2, 64);
        if ((t & 3) == 0) out[base_pt + pt] = s + bf[0];
    }
}

extern "C" void kernel_launch(void* const* d_in, const int* in_sizes, int n_in,
                              void* d_out, int out_size, void* d_ws, size_t ws_size,
                              hipStream_t stream) {
    (void)in_sizes; (void)n_in; (void)out_size; (void)ws_size;
    const float* coords = (const float*)d_in[0];
    const float* ow1 = (const float*)d_in[1];
    const float* ob1 = (const float*)d_in[2];
    const float* ow2 = (const float*)d_in[3];
    const float* ob2 = (const float*)d_in[4];
    const float* w0  = (const float*)d_in[5];
    const float* b0  = (const float*)d_in[6];
    const float* wh  = (const float*)d_in[7];
    const float* bh  = (const float*)d_in[8];
    const float* wf  = (const float*)d_in[9];
    const float* bf  = (const float*)d_in[10];
    float* out = (float*)d_out;
    f16* wt = (f16*)d_ws;   // 512 frags * 1KB = 512 KB

    prep_wt<<<512, 64, 0, stream>>>(wh, wt);
    siren_fused<<<524288 / MT, 512, 0, stream>>>(coords, ow1, ob1, ow2, ob2,
                                                 w0, b0, wt, bh, wf, bf, out);
}

// Round 6
// 450.455 us; speedup vs baseline: 1.3742x; 1.3742x over previous
//
#include <hip/hip_runtime.h>
#include <hip/hip_bf16.h>

typedef _Float16 f16;
typedef f16 f16x4 __attribute__((ext_vector_type(4)));
typedef f16 f16x8 __attribute__((ext_vector_type(8)));
typedef __fp16 h16x2 __attribute__((ext_vector_type(2)));
typedef __fp16 h16x4 __attribute__((ext_vector_type(4)));
typedef float f32x4 __attribute__((ext_vector_type(4)));
typedef float f32x16 __attribute__((ext_vector_type(16)));

#define MT 128          // points per block (2 blocks/CU -> 4 waves/SIMD)
#define LDST 260        // f16 LDS row stride: 520 B -> 2-way (free) bank pattern, 8B aligned
#define INV2PI 0.15915494309189535f

// ---------------- prep: fragment-major Wt ----------------
// wt layout: frag[(layer*8 + wcblk)*16 + kblk][lane][8]  (1 KB per frag, lane-major)
// A[i=lane&31][k = kblk*16 + (lane>>5)*8 + j] = wh[layer][k][wcblk*32 + (lane&31)]
__global__ __launch_bounds__(64)
void prep_wt(const float* __restrict__ wh, f16* __restrict__ wt) {
    const int b = blockIdx.x;                 // 512 = layer(4) x wcblk(8) x kblk(16)
    const int layer = b >> 7, wcblk = (b >> 4) & 7, kblk = b & 15;
    const int lane = threadIdx.x;
    const int l31 = lane & 31, lh = lane >> 5;
    const float* src = wh + layer * 65536 + (kblk * 16 + lh * 8) * 256 + wcblk * 32 + l31;
    f16x8 v;
#pragma unroll
    for (int j = 0; j < 8; j++) v[j] = (f16)src[j * 256];   // 128B-coalesced per half-wave
    *(f16x8*)(wt + b * 512 + lane * 8) = v;                  // 1KB coalesced store
}

// ---------------- fused SIREN ----------------
__device__ inline f16x8 lds_ld8(const f16* p) {
    // two 8B LDS loads (rows are 8B- but not 16B-aligned with LDST=260)
    f16x4 lo = *(const f16x4*)p;
    f16x4 hi = *(const f16x4*)(p + 4);
    return __builtin_shufflevector(lo, hi, 0, 1, 2, 3, 4, 5, 6, 7);
}

__device__ inline f16x4 pk4(float z0, float z1, float z2, float z3) {
    h16x2 a = __builtin_amdgcn_cvt_pkrtz(z0, z1);
    h16x2 b = __builtin_amdgcn_cvt_pkrtz(z2, z3);
    h16x4 r = __builtin_shufflevector(a, b, 0, 1, 2, 3);
    return __builtin_bit_cast(f16x4, r);
}

__global__ __launch_bounds__(512, 4)
void siren_fused(const float* __restrict__ coords,
                 const float* __restrict__ ow1, const float* __restrict__ ob1,
                 const float* __restrict__ ow2, const float* __restrict__ ob2,
                 const float* __restrict__ w0, const float* __restrict__ b0,
                 const f16* __restrict__ wt,    // fragment-major, see prep_wt
                 const float* __restrict__ bh,  // [4][256]
                 const float* __restrict__ wf,  // [256]
                 const float* __restrict__ bf,  // [1]
                 float* __restrict__ out) {
    __shared__ __align__(16) f16 Xs[MT * LDST];   // 66560 B activations
    __shared__ float om_rev[MT];                  // omega / (2*pi)
    __shared__ __align__(16) float crd[MT * 4];
    __shared__ __align__(16) float bh_s[256];
    __shared__ __align__(16) float wf_s[256];

    const int t = threadIdx.x;
    const long base_pt = (long)blockIdx.x * MT;

    // ---- stage coords + wf ----
    if (t < MT) ((f32x4*)crd)[t] = ((const f32x4*)(coords + base_pt * 4))[t];
    if (t < 256) wf_s[t] = wf[t];
    __syncthreads();

    // ---- omega predictor (fp32 vector; threads 0..127, one point each) ----
    if (t < MT) {
        const float c0 = crd[t * 4], c1 = crd[t * 4 + 1], c2 = crd[t * 4 + 2], c3 = crd[t * 4 + 3];
        float h[64];
#pragma unroll
        for (int j = 0; j < 64; j++) {
            float z = ob1[j] + c0 * ow1[j] + c1 * ow1[64 + j] + c2 * ow1[128 + j] + c3 * ow1[192 + j];
            h[j] = fmaxf(z, 0.f);
        }
        float z2 = ob2[0];
#pragma unroll
        for (int j = 0; j < 64; j++) z2 += h[j] * ow2[j];
        const float sig = 1.f / (1.f + __expf(-z2));
        om_rev[t] = (10.f + 90.f * sig) * INV2PI;
    }
    __syncthreads();

    // ---- layer 0 (K=4, fp32 vector): X = sin(omega*(coords@w0+b0)) ----
    // chunk-interleaved channels: thread q of a point's quad handles chunks q,q+4,q+8,q+12
    // (16 f16 each) -> quad writes land on disjoint banks (no 4-way conflict).
    {
        const int pt = t >> 2;
        const int q = t & 3;
        const float c0 = crd[pt * 4], c1 = crd[pt * 4 + 1], c2 = crd[pt * 4 + 2], c3 = crd[pt * 4 + 3];
        const float orv = om_rev[pt];
#pragma unroll
        for (int i = 0; i < 4; i++) {
            const int ch = (q + 4 * i) * 16;
#pragma unroll
            for (int c = 0; c < 16; c += 4) {
                f32x4 wv0 = *(const f32x4*)(w0 + 0 * 256 + ch + c);
                f32x4 wv1 = *(const f32x4*)(w0 + 1 * 256 + ch + c);
                f32x4 wv2 = *(const f32x4*)(w0 + 2 * 256 + ch + c);
                f32x4 wv3 = *(const f32x4*)(w0 + 3 * 256 + ch + c);
                f32x4 bv  = *(const f32x4*)(b0 + ch + c);
                float z[4];
#pragma unroll
                for (int j = 0; j < 4; j++) {
                    float zz = bv[j] + c0 * wv0[j] + c1 * wv1[j] + c2 * wv2[j] + c3 * wv3[j];
                    z[j] = __builtin_amdgcn_sinf(orv * zz);
                }
                *(f16x4*)&Xs[pt * LDST + ch + c] = pk4(z[0], z[1], z[2], z[3]);
            }
        }
    }
    __syncthreads();

    // ---- hidden layers: Z^T = Wt (A) x X (B), 32x32x16 f16 MFMA ----
    // 8 waves: 4 wcol-groups (2 wcblks, ct=2) x 2 prow-groups (64 rows, rt=2).
    // Explicit depth-3 A-prefetch ring: MFMA for kb depends on loads issued 3 iters
    // (~300+ cyc) earlier -> L1 latency hidden even at shallow compiler scheduling.
    const int lane = t & 63;
    const int wave = t >> 6;          // 8 waves
    const int l31 = lane & 31;
    const int lh = lane >> 5;         // half-wave: k-offset 8
    const int wcg = wave & 3;         // wcol group: 64 cols
    const int pr0 = (wave >> 2) * 64; // 64 point-rows per wave
    const int wc0 = wcg * 64;

    for (int layer = 0; layer < 4; layer++) {
        if (t < 256) bh_s[t] = bh[layer * 256 + t];   // consumed after mid-barrier

        // A frags for this wave: wcblk0 = wcg*2, second wcblk at +8192 f16
        const f16* afrag = wt + ((layer * 8 + wcg * 2) * 16) * 512 + lane * 8;
        const f16* bptr = &Xs[(pr0 + l31) * LDST + lh * 8];   // B: lane row = prow

        f32x16 acc[2][2];
#pragma unroll
        for (int ct = 0; ct < 2; ct++)
#pragma unroll
            for (int rt = 0; rt < 2; rt++)
#pragma unroll
                for (int j = 0; j < 16; j++) acc[ct][rt][j] = 0.f;

        f16x8 a0[3], a1[3];
#pragma unroll
        for (int d = 0; d < 3; d++) {
            a0[d] = *(const f16x8*)(afrag + d * 512);
            a1[d] = *(const f16x8*)(afrag + 8192 + d * 512);
        }

#pragma unroll
        for (int kb = 0; kb < 16; kb++) {
            const int s = kb % 3;
            f16x8 av0 = a0[s], av1 = a1[s];
            if (kb + 3 < 16) {                         // refill ring 3 iters ahead
                a0[s] = *(const f16x8*)(afrag + (kb + 3) * 512);
                a1[s] = *(const f16x8*)(afrag + 8192 + (kb + 3) * 512);
            }
            f16x8 bv0 = lds_ld8(bptr + 0 * 32 * LDST + kb * 16);
            f16x8 bv1 = lds_ld8(bptr + 1 * 32 * LDST + kb * 16);
            acc[0][0] = __builtin_amdgcn_mfma_f32_32x32x16_f16(av0, bv0, acc[0][0], 0, 0, 0);
            acc[0][1] = __builtin_amdgcn_mfma_f32_32x32x16_f16(av0, bv1, acc[0][1], 0, 0, 0);
            acc[1][0] = __builtin_amdgcn_mfma_f32_32x32x16_f16(av1, bv0, acc[1][0], 0, 0, 0);
            acc[1][1] = __builtin_amdgcn_mfma_f32_32x32x16_f16(av1, bv1, acc[1][1], 0, 0, 0);
        }
        __syncthreads();   // all Xs reads done; bh_s staged

        // epilogue: x = sin(om*(z+b)), write f16 back to Xs
        float orv[2];
#pragma unroll
        for (int rt = 0; rt < 2; rt++) orv[rt] = om_rev[pr0 + rt * 32 + l31];
#pragma unroll
        for (int ct = 0; ct < 2; ct++) {
#pragma unroll
            for (int g = 0; g < 4; g++) {
                const int wc = wc0 + ct * 32 + g * 8 + lh * 4;  // D row = (reg&3)+8*(reg>>2)+4*lh
                f32x4 bb = *(const f32x4*)&bh_s[wc];
#pragma unroll
                for (int rt = 0; rt < 2; rt++) {
                    const int prow = pr0 + rt * 32 + l31;       // D col = lane&31
                    float z[4];
#pragma unroll
                    for (int j = 0; j < 4; j++)
                        z[j] = __builtin_amdgcn_sinf(orv[rt] * (acc[ct][rt][g * 4 + j] + bb[j]));
                    *(f16x4*)&Xs[prow * LDST + wc] = pk4(z[0], z[1], z[2], z[3]);  // 8B write
                }
            }
        }
        __syncthreads();
    }

    // ---- final layer: out = X @ wf + bf (fp32 vector), chunk-interleaved ----
    {
        const int pt = t >> 2;
        const int q = t & 3;
        const f16* xrow = &Xs[pt * LDST];
        float s = 0.f;
#pragma unroll
        for (int i = 0; i < 4; i++) {
            const int ch = (q + 4 * i) * 16;
#pragma unroll
            for (int c = 0; c < 16; c += 4) {
                f16x4 xv = *(const f16x4*)(xrow + ch + c);
                f32x4 wv = *(const f32x4*)&wf_s[ch + c];
                s += (float)xv[0] * wv[0] + (float)xv[1] * wv[1]
                   + (float)xv[2] * wv[2] + (float)xv[3] * wv[3];
            }
        }
        s += __shfl_xor(s, 1, 64);
        s += __shfl_xor(s, 2, 64);
        if (q == 0) out[base_pt + pt] = s + bf[0];
    }
}

extern "C" void kernel_launch(void* const* d_in, const int* in_sizes, int n_in,
                              void* d_out, int out_size, void* d_ws, size_t ws_size,
                              hipStream_t stream) {
    (void)in_sizes; (void)n_in; (void)out_size; (void)ws_size;
    const float* coords = (const float*)d_in[0];
    const float* ow1 = (const float*)d_in[1];
    const float* ob1 = (const float*)d_in[2];
    const float* ow2 = (const float*)d_in[3];
    const float* ob2 = (const float*)d_in[4];
    const float* w0  = (const float*)d_in[5];
    const float* b0  = (const float*)d_in[6];
    const float* wh  = (const float*)d_in[7];
    const float* bh  = (const float*)d_in[8];
    const float* wf  = (const float*)d_in[9];
    const float* bf  = (const float*)d_in[10];
    float* out = (float*)d_out;
    f16* wt = (f16*)d_ws;   // 512 frags * 1KB = 512 KB

    prep_wt<<<512, 64, 0, stream>>>(wh, wt);
    siren_fused<<<524288 / MT, 512, 0, stream>>>(coords, ow1, ob1, ow2, ob2,
                                                 w0, b0, wt, bh, wf, bf, out);
}